// Round 13
// baseline (132.646 us; speedup 1.0000x reference)
//
#include <hip/hip_runtime.h>

#define IMG_H 720
#define IMG_W 1280
#define HW (IMG_H * IMG_W)

#define TX 32
#define TY 16
#define NBX (IMG_W / TX)   // 40
#define NBY (IMG_H / TY)   // 45
#define NBLK (NBX * NBY)   // 1800 blocks; each block does BOTH images
#define LW2 40             // f2 columns per LDS row (38 used)
#define LH (TY + 6)        // 22

// k = sqrt(50*log2(e)); w = exp2(-((k*v - k*c)^2 + r2*S2SCALE))
#define KSCALE 8.493218148592486f
#define INVK   0.11774100235949044f
#define S2SCALE 0.028853900817779268f  // 1/(50*ln2)

typedef float f2 __attribute__((ext_vector_type(2)));

#if defined(__has_builtin)
#if __has_builtin(__builtin_amdgcn_exp2f)
#define EXP2(x) __builtin_amdgcn_exp2f(x)
#else
#define EXP2(x) exp2f(x)
#endif
#if __has_builtin(__builtin_amdgcn_rcpf)
#define RCP(x) __builtin_amdgcn_rcpf(x)
#else
#define RCP(x) (1.0f / (x))
#endif
#else
#define EXP2(x) exp2f(x)
#define RCP(x) (1.0f / (x))
#endif

// spatial sums ry2+rx2 ∈ {0,1,2,4,5,8,9,10,13,18} -> index 0..9
__device__ constexpr int MIDX[19] = {0, 1, 2, -1, 3, 4, -1, -1, 5, 6,
                                     7, -1, -1, 8, -1, -1, -1, -1, 9};

// MODE 0: real bilateral tap (hardware exp2).
// MODE 1: probe-only — exp2 replaced by one pk_mul (isolates exp issue cost).
template <int MODE>
__device__ __forceinline__ void tap(f2 v, f2 nck, f2 s2p, f2& aw, f2& aiw) {
    f2 dd = v + nck;                               // v - ck
    f2 e = __builtin_elementwise_fma(dd, dd, s2p); // dd^2 + s2 (positive)
    f2 w;
    if constexpr (MODE == 0) {
        w.x = EXP2(-e.x);   // neg folds into v_exp_f32 src modifier
        w.y = EXP2(-e.y);
    } else {
        w = e * 0.013532f;  // one v_pk_mul_f32 — deterministic, bounded
    }
    aw += w;
    aiw = __builtin_elementwise_fma(w, v, aiw);
}

template <int RY2, int MODE>
__device__ __forceinline__ void do_row_t(const f2* __restrict__ rowptr,
                                         f2 nck0, f2 nck1,
                                         f2& aw0, f2& aiw0, f2& aw1, f2& aiw1,
                                         const f2 (&s2)[10]) {
    f2 f[8];
    *(float4*)(&f[0]) = *(const float4*)(rowptr + 0);
    *(float4*)(&f[2]) = *(const float4*)(rowptr + 2);
    *(float4*)(&f[4]) = *(const float4*)(rowptr + 4);
    *(float4*)(&f[6]) = *(const float4*)(rowptr + 6);
#pragma unroll
    for (int dx = 0; dx < 7; ++dx) {
        const int sidx = MIDX[RY2 + (dx - 3) * (dx - 3)];  // compile-time
        tap<MODE>(f[dx], nck0, s2[sidx], aw0, aiw0);
        tap<MODE>(f[dx + 1], nck1, s2[sidx], aw1, aiw1);
    }
}

template <int MODE>
__device__ __forceinline__ void bilateral_body(const float* __restrict__ I,
                                               float* __restrict__ O, int b) {
    int bx = b % NBX, by = b / NBX;
    int tx0 = bx * TX, ty0 = by * TY;
    int tid = threadIdx.x;

    __shared__ f2 S[LH][LW2];
    const float* img0 = I;
    const float* img1 = I + HW;

    // ---- stage both images, interleaved {img0,img1} per f2, k-pre-scaled ----
    bool interior = (bx >= 1) && (bx <= NBX - 2) && (by >= 1) && (by <= NBY - 2);
    if (interior) {
        if (tid < LH * (LW2 / 4)) {
            int r = tid / (LW2 / 4), q = tid % (LW2 / 4);
            int gy = ty0 - 3 + r, gx = tx0 - 3 + q * 4;
            float4 a0 = *(const float4*)(img0 + gy * IMG_W + gx);
            float4 a1 = *(const float4*)(img1 + gy * IMG_W + gx);
            float4 w0, w1;
            w0.x = a0.x * KSCALE; w0.y = a1.x * KSCALE;
            w0.z = a0.y * KSCALE; w0.w = a1.y * KSCALE;
            w1.x = a0.z * KSCALE; w1.y = a1.z * KSCALE;
            w1.z = a0.w * KSCALE; w1.w = a1.w * KSCALE;
            *(float4*)(&S[r][q * 4]) = w0;
            *(float4*)(&S[r][q * 4 + 2]) = w1;
        }
    } else {
#pragma unroll
        for (int i = 0; i < 4; ++i) {
            int idx = tid + i * 256;
            if (idx < LH * LW2) {
                int r = idx / LW2, c = idx % LW2;
                int gy = ty0 - 3 + r, gx = tx0 - 3 + c;
                float v0 = 0.f, v1 = 0.f;
                if (gy >= 0 && gy < IMG_H && gx >= 0 && gx < IMG_W) {
                    v0 = img0[gy * IMG_W + gx];
                    v1 = img1[gy * IMG_W + gx];
                }
                f2 t = {v0 * KSCALE, v1 * KSCALE};
                S[r][c] = t;
            }
        }
    }
    __syncthreads();

    // ---- spatial constants: compile-time indexed; UNPINNED (R13 change) so
    // the compiler may place them in SGPRs (VOP3P broadcasts sgpr srcs). ----
    const float sv[10] = {0.f, 1.f, 2.f, 4.f, 5.f, 8.f, 9.f, 10.f, 13.f, 18.f};
    f2 s2c[10];
#pragma unroll
    for (int j = 0; j < 10; ++j) {
        float s = sv[j] * S2SCALE;
        s2c[j].x = s;
        s2c[j].y = s;
    }

    // ---- compute: 2 pixel-pairs (4 outputs) per thread ----
    int px = tid & 15;
    int py = tid >> 4;
    int x0 = px * 2;

    f2 aw0 = {0.f, 0.f}, aw1 = {0.f, 0.f};
    f2 aiw0 = {0.f, 0.f}, aiw1 = {0.f, 0.f};
    f2 nck0, nck1;

    // Row 3 first: centers come from this row's registers.
    {
        const f2* rowptr = &S[py + 3][x0];
        f2 f[8];
        *(float4*)(&f[0]) = *(const float4*)(rowptr + 0);
        *(float4*)(&f[2]) = *(const float4*)(rowptr + 2);
        *(float4*)(&f[4]) = *(const float4*)(rowptr + 4);
        *(float4*)(&f[6]) = *(const float4*)(rowptr + 6);
        nck0 = -f[3];
        nck1 = -f[4];
#pragma unroll
        for (int dx = 0; dx < 7; ++dx) {
            const int sidx = MIDX[(dx - 3) * (dx - 3)];
            tap<MODE>(f[dx], nck0, s2c[sidx], aw0, aiw0);
            tap<MODE>(f[dx + 1], nck1, s2c[sidx], aw1, aiw1);
        }
    }
    do_row_t<9, MODE>(&S[py + 0][x0], nck0, nck1, aw0, aiw0, aw1, aiw1, s2c);
    do_row_t<4, MODE>(&S[py + 1][x0], nck0, nck1, aw0, aiw0, aw1, aiw1, s2c);
    do_row_t<1, MODE>(&S[py + 2][x0], nck0, nck1, aw0, aiw0, aw1, aiw1, s2c);
    do_row_t<1, MODE>(&S[py + 4][x0], nck0, nck1, aw0, aiw0, aw1, aiw1, s2c);
    do_row_t<4, MODE>(&S[py + 5][x0], nck0, nck1, aw0, aiw0, aw1, aiw1, s2c);
    do_row_t<9, MODE>(&S[py + 6][x0], nck0, nck1, aw0, aiw0, aw1, aiw1, s2c);

    int oy = ty0 + py;
    float2 r0, r1;
    r0.x = aiw0.x * RCP(aw0.x) * INVK;
    r0.y = aiw1.x * RCP(aw1.x) * INVK;
    r1.x = aiw0.y * RCP(aw0.y) * INVK;
    r1.y = aiw1.y * RCP(aw1.y) * INVK;
    *(float2*)(O + (size_t)oy * IMG_W + tx0 + x0) = r0;
    *(float2*)(O + HW + (size_t)oy * IMG_W + tx0 + x0) = r1;
}

// Real kernel (R11 + unpinned constants).
__global__ __launch_bounds__(256, 8) void bilateral_pk(
    const float* __restrict__ I, float* __restrict__ O) {
    bilateral_body<0>(I, O, blockIdx.x);
}

// Probe A: identical body, 4x grid, writes scratch -> visible in rocprof.
__global__ __launch_bounds__(256, 8) void bilateral_probeA(
    const float* __restrict__ I, float* __restrict__ O) {
    bilateral_body<0>(I, O, blockIdx.x % NBLK);
}

// Probe B: exp2 -> pk_mul, 8x grid. dur_A/4 - dur_B/8 isolates exp cost.
__global__ __launch_bounds__(256, 8) void bilateral_probeB(
    const float* __restrict__ I, float* __restrict__ O) {
    bilateral_body<1>(I, O, blockIdx.x % NBLK);
}

extern "C" void kernel_launch(void* const* d_in, const int* in_sizes, int n_in,
                              void* d_out, int out_size, void* d_ws, size_t ws_size,
                              hipStream_t stream) {
    const float* I = (const float*)d_in[0];
    float* O = (float*)d_out;

    bilateral_pk<<<NBLK, 256, 0, stream>>>(I, O);

    // Diagnostic probes (scratch only; d_out already final).
    const size_t probe_need = (size_t)HW * 2 * sizeof(float);
    if (d_ws != nullptr && ws_size >= probe_need) {
        float* W = (float*)d_ws;
        bilateral_probeA<<<NBLK * 4, 256, 0, stream>>>(I, W);
        bilateral_probeB<<<NBLK * 8, 256, 0, stream>>>(I, W);
    }
}

// Round 14
// 21.688 us; speedup vs baseline: 6.1160x; 6.1160x over previous
//
#include <hip/hip_runtime.h>
#include <hip/hip_fp16.h>

#define IMG_H 720
#define IMG_W 1280
#define HW (IMG_H * IMG_W)

#define TX 32
#define TY 16
#define NBX (IMG_W / TX)   // 40
#define NBY (IMG_H / TY)   // 45
#define NBLK (NBX * NBY)   // 1800 blocks; each block does BOTH images
#define LW2 40             // half2 columns per LDS row (38 used); 160B pitch
#define LH (TY + 6)        // 22

// k = sqrt(50*log2(e)); w = exp2(-((k*v - k*c)^2 + r2*S2SCALE))
#define KSCALE 8.493218148592486f
#define INVK   0.11774100235949044f
#define S2SCALE 0.028853900817779268f  // 1/(50*ln2)

#if defined(__has_builtin)
#if __has_builtin(__builtin_amdgcn_rcpf)
#define RCP(x) __builtin_amdgcn_rcpf(x)
#else
#define RCP(x) (1.0f / (x))
#endif
#else
#define RCP(x) (1.0f / (x))
#endif

// spatial sums ry2+rx2 ∈ {0,1,2,4,5,8,9,10,13,18} -> index 0..9
__device__ constexpr int MIDX[19] = {0, 1, 2, -1, 3, 4, -1, -1, 5, 6,
                                     7, -1, -1, 8, -1, -1, -1, -1, 9};

// One packed tap = this (dy,dx) tap for BOTH images of one pixel.
// All half2 ops via HIP intrinsics -> ISel emits v_pk_*_f16 / v_exp_f16
// with correct semantics (R9/R10 lesson: no hand-written VOP3P asm).
// 5 pk-f16 (2cy each) + 2 trans per tap; exp measured ~free (R13 probe).
__device__ __forceinline__ void tap(__half2 v, __half2 ck, __half2 ns2,
                                    __half2& aw, __half2& aiw) {
    __half2 dd = __hsub2(v, ck);
    __half2 dn = __hsub2(ck, v);
    __half2 e = __hfma2(dd, dn, ns2);   // -(dd^2) - s2
    __half2 w = h2exp2(e);
    aw = __hadd2(aw, w);
    aiw = __hfma2(w, v, aiw);
}

template <int RY2>
__device__ __forceinline__ void do_row_t(const __half2* __restrict__ rowptr,
                                         __half2 ck0, __half2 ck1,
                                         __half2& aw0, __half2& aiw0,
                                         __half2& aw1, __half2& aiw1,
                                         const __half2 (&ns2)[10]) {
    __half2 f[8];
    *(uint2*)(&f[0]) = *(const uint2*)(rowptr + 0);  // 4x ds_read_b64,
    *(uint2*)(&f[2]) = *(const uint2*)(rowptr + 2);  // 8B-aligned, 16-lane
    *(uint2*)(&f[4]) = *(const uint2*)(rowptr + 4);  // phase covers all 32
    *(uint2*)(&f[6]) = *(const uint2*)(rowptr + 6);  // banks exactly once
#pragma unroll
    for (int dx = 0; dx < 7; ++dx) {
        const int sidx = MIDX[RY2 + (dx - 3) * (dx - 3)];  // compile-time
        tap(f[dx], ck0, ns2[sidx], aw0, aiw0);
        tap(f[dx + 1], ck1, ns2[sidx], aw1, aiw1);
    }
}

__global__ __launch_bounds__(256, 8) void bilateral_h2(
    const float* __restrict__ I, float* __restrict__ O) {
    int b = blockIdx.x;
    int bx = b % NBX, by = b / NBX;
    int tx0 = bx * TX, ty0 = by * TY;
    int tid = threadIdx.x;

    __shared__ __half2 S[LH][LW2];
    const float* img0 = I;
    const float* img1 = I + HW;

    // ---- stage both images as half2{img0,img1}, k-pre-scaled, RNE ----
    bool interior = (bx >= 1) && (bx <= NBX - 2) && (by >= 1) && (by <= NBY - 2);
    if (interior) {
        // 220 chunks of 4 pixel-cols; no clamping needed (R11-verified bounds).
        if (tid < LH * (LW2 / 4)) {
            int r = tid / (LW2 / 4), q = tid % (LW2 / 4);
            int gy = ty0 - 3 + r, gx = tx0 - 3 + q * 4;
            float4 a0 = *(const float4*)(img0 + gy * IMG_W + gx);
            float4 a1 = *(const float4*)(img1 + gy * IMG_W + gx);
            __half2 h0 = __floats2half2_rn(a0.x * KSCALE, a1.x * KSCALE);
            __half2 h1 = __floats2half2_rn(a0.y * KSCALE, a1.y * KSCALE);
            __half2 h2 = __floats2half2_rn(a0.z * KSCALE, a1.z * KSCALE);
            __half2 h3 = __floats2half2_rn(a0.w * KSCALE, a1.w * KSCALE);
            uint2 lo, hi;
            lo.x = *(unsigned int*)&h0; lo.y = *(unsigned int*)&h1;
            hi.x = *(unsigned int*)&h2; hi.y = *(unsigned int*)&h3;
            *(uint2*)(&S[r][q * 4]) = lo;
            *(uint2*)(&S[r][q * 4 + 2]) = hi;
        }
    } else {
#pragma unroll
        for (int i = 0; i < 4; ++i) {
            int idx = tid + i * 256;
            if (idx < LH * LW2) {
                int r = idx / LW2, c = idx % LW2;
                int gy = ty0 - 3 + r, gx = tx0 - 3 + c;
                float v0 = 0.f, v1 = 0.f;
                if (gy >= 0 && gy < IMG_H && gx >= 0 && gx < IMG_W) {
                    v0 = img0[gy * IMG_W + gx];
                    v1 = img1[gy * IMG_W + gx];
                }
                S[r][c] = __floats2half2_rn(v0 * KSCALE, v1 * KSCALE);
            }
        }
    }
    __syncthreads();

    // ---- negative spatial constants as half2 (compile-time foldable) ----
    const float sv[10] = {0.f, 1.f, 2.f, 4.f, 5.f, 8.f, 9.f, 10.f, 13.f, 18.f};
    __half2 ns2c[10];
#pragma unroll
    for (int j = 0; j < 10; ++j)
        ns2c[j] = __float2half2_rn(-sv[j] * S2SCALE);

    // ---- compute: 2 pixel-pairs (4 outputs) per thread ----
    int px = tid & 15;
    int py = tid >> 4;
    int x0 = px * 2;

    __half2 zero = __float2half2_rn(0.f);
    __half2 aw0 = zero, aw1 = zero, aiw0 = zero, aiw1 = zero;
    __half2 ck0, ck1;

    // Row 3 first: centers come from this row's registers.
    {
        const __half2* rowptr = &S[py + 3][x0];
        __half2 f[8];
        *(uint2*)(&f[0]) = *(const uint2*)(rowptr + 0);
        *(uint2*)(&f[2]) = *(const uint2*)(rowptr + 2);
        *(uint2*)(&f[4]) = *(const uint2*)(rowptr + 4);
        *(uint2*)(&f[6]) = *(const uint2*)(rowptr + 6);
        ck0 = f[3];
        ck1 = f[4];
#pragma unroll
        for (int dx = 0; dx < 7; ++dx) {
            const int sidx = MIDX[(dx - 3) * (dx - 3)];
            tap(f[dx], ck0, ns2c[sidx], aw0, aiw0);
            tap(f[dx + 1], ck1, ns2c[sidx], aw1, aiw1);
        }
    }
    do_row_t<9>(&S[py + 0][x0], ck0, ck1, aw0, aiw0, aw1, aiw1, ns2c);
    do_row_t<4>(&S[py + 1][x0], ck0, ck1, aw0, aiw0, aw1, aiw1, ns2c);
    do_row_t<1>(&S[py + 2][x0], ck0, ck1, aw0, aiw0, aw1, aiw1, ns2c);
    do_row_t<1>(&S[py + 4][x0], ck0, ck1, aw0, aiw0, aw1, aiw1, ns2c);
    do_row_t<4>(&S[py + 5][x0], ck0, ck1, aw0, aiw0, aw1, aiw1, ns2c);
    do_row_t<9>(&S[py + 6][x0], ck0, ck1, aw0, aiw0, aw1, aiw1, ns2c);

    // ---- f32 epilogue ----
    int oy = ty0 + py;
    float2 r0, r1;
    r0.x = __low2float(aiw0) * RCP(__low2float(aw0)) * INVK;
    r0.y = __low2float(aiw1) * RCP(__low2float(aw1)) * INVK;
    r1.x = __high2float(aiw0) * RCP(__high2float(aw0)) * INVK;
    r1.y = __high2float(aiw1) * RCP(__high2float(aw1)) * INVK;
    *(float2*)(O + (size_t)oy * IMG_W + tx0 + x0) = r0;
    *(float2*)(O + HW + (size_t)oy * IMG_W + tx0 + x0) = r1;
}

extern "C" void kernel_launch(void* const* d_in, const int* in_sizes, int n_in,
                              void* d_out, int out_size, void* d_ws, size_t ws_size,
                              hipStream_t stream) {
    const float* I = (const float*)d_in[0];
    float* O = (float*)d_out;
    bilateral_h2<<<NBLK, 256, 0, stream>>>(I, O);
}

// Round 15
// 19.354 us; speedup vs baseline: 6.8538x; 1.1206x over previous
//
#include <hip/hip_runtime.h>

#define IMG_H 720
#define IMG_W 1280
#define HW (IMG_H * IMG_W)

#define TX 32
#define TY 16
#define NBX (IMG_W / TX)   // 40
#define NBY (IMG_H / TY)   // 45
#define NBLK (NBX * NBY)   // 1800 blocks; each block does BOTH images
#define LW2 40             // f2 columns per LDS row (38 used)
#define LH (TY + 6)        // 22

// k = sqrt(50*log2(e)); w = exp2(-((k*v - k*c)^2 + r2*S2SCALE))
#define KSCALE 8.493218148592486f
#define INVK   0.11774100235949044f
#define S2SCALE 0.028853900817779268f  // 1/(50*ln2)

typedef float f2 __attribute__((ext_vector_type(2)));

#if defined(__has_builtin)
#if __has_builtin(__builtin_amdgcn_exp2f)
#define EXP2(x) __builtin_amdgcn_exp2f(x)
#else
#define EXP2(x) exp2f(x)
#endif
#if __has_builtin(__builtin_amdgcn_rcpf)
#define RCP(x) __builtin_amdgcn_rcpf(x)
#else
#define RCP(x) (1.0f / (x))
#endif
#else
#define EXP2(x) exp2f(x)
#define RCP(x) (1.0f / (x))
#endif

// spatial sums ry2+rx2 ∈ {0,1,2,4,5,8,9,10,13,18} -> index 0..9
__device__ constexpr int MIDX[19] = {0, 1, 2, -1, 3, 4, -1, -1, 5, 6,
                                     7, -1, -1, 8, -1, -1, -1, -1, 9};

// One packed tap = this (dy,dx) tap for BOTH images of one pixel.
// Native v2f32 ops -> ISel emits v_pk_add_f32/v_pk_fma_f32 with correct
// op_sel (R9/R10 lesson: never hand-encode VOP3P modifier defaults).
// Ladder evidence: f32-pk is the floor — fp16-pk regressed (R14, same
// issue rate + h2exp2 unpack overhead), VALU-exp regressed (R3),
// 8px/thread regressed (R12, halves wave count). exp2 is ~free (R13
// probe: trans pipe co-issues, ~1cy marginal per exp).
__device__ __forceinline__ void tap(f2 v, f2 nck, f2 s2p, f2& aw, f2& aiw) {
    f2 dd = v + nck;                               // v - ck
    f2 e = __builtin_elementwise_fma(dd, dd, s2p); // dd^2 + s2 (positive)
    f2 w;
    w.x = EXP2(-e.x);   // neg folds into v_exp_f32 src modifier
    w.y = EXP2(-e.y);
    aw += w;
    aiw = __builtin_elementwise_fma(w, v, aiw);
}

template <int RY2>
__device__ __forceinline__ void do_row_t(const f2* __restrict__ rowptr,
                                         f2 nck0, f2 nck1,
                                         f2& aw0, f2& aiw0, f2& aw1, f2& aiw1,
                                         const f2 (&s2)[10]) {
    f2 f[8];
    *(float4*)(&f[0]) = *(const float4*)(rowptr + 0);
    *(float4*)(&f[2]) = *(const float4*)(rowptr + 2);
    *(float4*)(&f[4]) = *(const float4*)(rowptr + 4);
    *(float4*)(&f[6]) = *(const float4*)(rowptr + 6);
#pragma unroll
    for (int dx = 0; dx < 7; ++dx) {
        const int sidx = MIDX[RY2 + (dx - 3) * (dx - 3)];  // compile-time
        tap(f[dx], nck0, s2[sidx], aw0, aiw0);
        tap(f[dx + 1], nck1, s2[sidx], aw1, aiw1);
    }
}

__global__ __launch_bounds__(256, 8) void bilateral_pk(
    const float* __restrict__ I, float* __restrict__ O) {
    int b = blockIdx.x;
    int bx = b % NBX, by = b / NBX;
    int tx0 = bx * TX, ty0 = by * TY;
    int tid = threadIdx.x;

    __shared__ f2 S[LH][LW2];
    const float* img0 = I;
    const float* img1 = I + HW;

    // ---- stage both images, interleaved {img0,img1} per f2, k-pre-scaled ----
    bool interior = (bx >= 1) && (bx <= NBX - 2) && (by >= 1) && (by <= NBY - 2);
    if (interior) {
        // 220 chunks of 4 f2-cols; interior never needs clamping
        // (bx<=38 -> max gx+3 = 1252 < 1280; bx>=1 -> min gx = 29).
        if (tid < LH * (LW2 / 4)) {
            int r = tid / (LW2 / 4), q = tid % (LW2 / 4);
            int gy = ty0 - 3 + r, gx = tx0 - 3 + q * 4;
            float4 a0 = *(const float4*)(img0 + gy * IMG_W + gx);
            float4 a1 = *(const float4*)(img1 + gy * IMG_W + gx);
            float4 w0, w1;
            w0.x = a0.x * KSCALE; w0.y = a1.x * KSCALE;
            w0.z = a0.y * KSCALE; w0.w = a1.y * KSCALE;
            w1.x = a0.z * KSCALE; w1.y = a1.z * KSCALE;
            w1.z = a0.w * KSCALE; w1.w = a1.w * KSCALE;
            *(float4*)(&S[r][q * 4]) = w0;
            *(float4*)(&S[r][q * 4 + 2]) = w1;
        }
    } else {
#pragma unroll
        for (int i = 0; i < 4; ++i) {
            int idx = tid + i * 256;
            if (idx < LH * LW2) {
                int r = idx / LW2, c = idx % LW2;
                int gy = ty0 - 3 + r, gx = tx0 - 3 + c;
                float v0 = 0.f, v1 = 0.f;
                if (gy >= 0 && gy < IMG_H && gx >= 0 && gx < IMG_W) {
                    v0 = img0[gy * IMG_W + gx];
                    v1 = img1[gy * IMG_W + gx];
                }
                f2 t = {v0 * KSCALE, v1 * KSCALE};
                S[r][c] = t;
            }
        }
    }
    __syncthreads();

    // ---- spatial constants: compile-time indexed, unpinned (compiler may
    // hold them in SGPRs; VOP3P broadcasts 32-bit sgpr srcs to both halves) ----
    const float sv[10] = {0.f, 1.f, 2.f, 4.f, 5.f, 8.f, 9.f, 10.f, 13.f, 18.f};
    f2 s2c[10];
#pragma unroll
    for (int j = 0; j < 10; ++j) {
        float s = sv[j] * S2SCALE;
        s2c[j].x = s;
        s2c[j].y = s;
    }

    // ---- compute: 2 pixel-pairs (4 outputs) per thread ----
    int px = tid & 15;
    int py = tid >> 4;
    int x0 = px * 2;

    f2 aw0 = {0.f, 0.f}, aw1 = {0.f, 0.f};
    f2 aiw0 = {0.f, 0.f}, aiw1 = {0.f, 0.f};
    f2 nck0, nck1;

    // Row 3 first: centers come from this row's registers.
    {
        const f2* rowptr = &S[py + 3][x0];
        f2 f[8];
        *(float4*)(&f[0]) = *(const float4*)(rowptr + 0);
        *(float4*)(&f[2]) = *(const float4*)(rowptr + 2);
        *(float4*)(&f[4]) = *(const float4*)(rowptr + 4);
        *(float4*)(&f[6]) = *(const float4*)(rowptr + 6);
        nck0 = -f[3];
        nck1 = -f[4];
#pragma unroll
        for (int dx = 0; dx < 7; ++dx) {
            const int sidx = MIDX[(dx - 3) * (dx - 3)];
            tap(f[dx], nck0, s2c[sidx], aw0, aiw0);
            tap(f[dx + 1], nck1, s2c[sidx], aw1, aiw1);
        }
    }
    do_row_t<9>(&S[py + 0][x0], nck0, nck1, aw0, aiw0, aw1, aiw1, s2c);
    do_row_t<4>(&S[py + 1][x0], nck0, nck1, aw0, aiw0, aw1, aiw1, s2c);
    do_row_t<1>(&S[py + 2][x0], nck0, nck1, aw0, aiw0, aw1, aiw1, s2c);
    do_row_t<1>(&S[py + 4][x0], nck0, nck1, aw0, aiw0, aw1, aiw1, s2c);
    do_row_t<4>(&S[py + 5][x0], nck0, nck1, aw0, aiw0, aw1, aiw1, s2c);
    do_row_t<9>(&S[py + 6][x0], nck0, nck1, aw0, aiw0, aw1, aiw1, s2c);

    int oy = ty0 + py;
    float2 r0, r1;
    r0.x = aiw0.x * RCP(aw0.x) * INVK;  // img0, col x0
    r0.y = aiw1.x * RCP(aw1.x) * INVK;  // img0, col x0+1
    r1.x = aiw0.y * RCP(aw0.y) * INVK;  // img1, col x0
    r1.y = aiw1.y * RCP(aw1.y) * INVK;  // img1, col x0+1
    *(float2*)(O + (size_t)oy * IMG_W + tx0 + x0) = r0;
    *(float2*)(O + HW + (size_t)oy * IMG_W + tx0 + x0) = r1;
}

extern "C" void kernel_launch(void* const* d_in, const int* in_sizes, int n_in,
                              void* d_out, int out_size, void* d_ws, size_t ws_size,
                              hipStream_t stream) {
    const float* I = (const float*)d_in[0];
    float* O = (float*)d_out;
    bilateral_pk<<<NBLK, 256, 0, stream>>>(I, O);
}